// Round 14
// baseline (214.066 us; speedup 1.0000x reference)
//
#include <hip/hip_runtime.h>
#include <hip/hip_bf16.h>

using bf16 = __hip_bfloat16;

constexpr int B_ = 32, S_ = 4096, V_ = 256, E_ = 128, H_ = 256, NM_ = 16;
constexpr int GH = 2 * H_;        // 512
constexpr int NC = 128, L_ = 32;  // chunked scan: 128 chunks of 32 steps

typedef __attribute__((ext_vector_type(8))) short bf16x8;
typedef __attribute__((ext_vector_type(4))) float f32x4;

__device__ __forceinline__ float b2f(unsigned short u) {
  union { float f; unsigned int i; } x; x.i = ((unsigned int)u) << 16; return x.f;
}
// RNE bf16 pack, no NaN path (values finite here)
__device__ __forceinline__ unsigned short f2b(float f) {
  unsigned int i = __builtin_bit_cast(unsigned int, f);
  return (unsigned short)((i + 0x7fffu + ((i >> 16) & 1u)) >> 16);
}

// h_t = a*h_{t-1} + bt;  a = sigmoid(-gate), bt = sigmoid(gate)*g(hid)
__device__ __forceinline__ void step_ab(float gate, float hid, float& a, float& bt) {
  const float LOG2E = 1.4426950408889634f;
  float e  = __builtin_amdgcn_exp2f(gate * LOG2E);
  a = __builtin_amdgcn_rcpf(1.0f + e);
  float sn = __builtin_amdgcn_rcpf(1.0f + __builtin_amdgcn_exp2f(-hid * LOG2E));
  float g  = (hid >= 0.0f) ? (hid + 0.5f) : sn;
  bt = (1.0f - a) * g;
}

// A-tile LDS swizzle: logical (row, byte-col) -> LDS byte offset
#define ATS(row, bcol) (((row) << 9) | ((bcol) ^ (((row) & 7) << 4)))

// gh2 layout: [b][c][ch][t] u32 (a | b' packed bf16); chunk base (u32): (b*NC+c)*256*32
// b' carries the folded residual: replaying y_t = a y_{t-1} + b' yields h_scan + residual.

// ---------------------------------------------------------------- tables
__global__ __launch_bounds__(256) void build_tables(
    const float* __restrict__ emb, const float* __restrict__ W0,
    const float* __restrict__ b0, const float* __restrict__ Walign,
    const float* __restrict__ Wl, float* __restrict__ T0, bf16* __restrict__ Wpk) {
  const int v = blockIdx.x;
  const int t = threadIdx.x;
  __shared__ float e[E_];
  if (t < E_) e[t] = emb[v * E_ + t];
  __syncthreads();
  const float4* w0g = (const float4*)(W0 + (size_t)t * E_);
  const float4* w0h = (const float4*)(W0 + (size_t)(t + 256) * E_);
  const float4* wal = (const float4*)(Walign + (size_t)t * E_);
  float g = b0[t], hd = b0[t + 256], al = 0.0f;
  #pragma unroll 8
  for (int k = 0; k < E_ / 4; ++k) {
    float4 ev = *(const float4*)(e + 4 * k);
    float4 ga = w0g[k]; g  += ga.x * ev.x + ga.y * ev.y + ga.z * ev.z + ga.w * ev.w;
    float4 hb = w0h[k]; hd += hb.x * ev.x + hb.y * ev.y + hb.z * ev.z + hb.w * ev.w;
    float4 aw = wal[k]; al += aw.x * ev.x + aw.y * ev.y + aw.z * ev.z + aw.w * ev.w;
  }
  float a, btv; step_ab(g, hd, a, btv);
  T0[(size_t)v * 768 + t]       = a;
  T0[(size_t)v * 768 + 256 + t] = btv;
  T0[(size_t)v * 768 + 512 + t] = al;

  const int fid = v * 256 + t;
  if (fid < 32768) {
    const int layer = fid >> 14;
    const int kk   = (fid >> 11) & 7;
    const int grp  = (fid >> 6) & 31;
    const int lane = fid & 63;
    const int row = grp * 16 + (lane & 15);
    const int k0  = kk * 32 + (lane >> 4) * 8;
    const float* src = Wl + (((size_t)layer * 512 + row) * 256 + k0);
    bf16* dst = Wpk + (size_t)fid * 8;
    #pragma unroll
    for (int e2 = 0; e2 < 8; ++e2) dst[e2] = __float2bfloat16(src[e2]);
  }
}

// ---------------------------------------------------------------- layer-0 scan A
__global__ __launch_bounds__(256) void scanA_l0(const int* __restrict__ x, const float* __restrict__ T0,
                                                float* __restrict__ cAB) {
  const int b = blockIdx.y;
  const int wv = threadIdx.x >> 6, lane = threadIdx.x & 63;
  const int c = blockIdx.x * 4 + wv;
  const int t4 = lane * 4;
  const int* xp = x + (size_t)b * S_ + (size_t)c * L_;
  float A0=1,A1=1,A2=1,A3=1, B0=0,B1=0,B2=0,B3=0;
  #pragma unroll 4
  for (int t = 0; t < L_; ++t) {
    const float* tp = T0 + (size_t)xp[t] * 768;
    float4 a4 = *(const float4*)(tp + t4);
    float4 b4 = *(const float4*)(tp + 256 + t4);
    A0 = a4.x*A0; B0 = a4.x*B0 + b4.x;
    A1 = a4.y*A1; B1 = a4.y*B1 + b4.y;
    A2 = a4.z*A2; B2 = a4.z*B2 + b4.z;
    A3 = a4.w*A3; B3 = a4.w*B3 + b4.w;
  }
  float* o = cAB + (size_t)(b * NC + c) * 2 * H_;
  *(float4*)(o + t4)      = make_float4(A0, A1, A2, A3);
  *(float4*)(o + H_ + t4) = make_float4(B0, B1, B2, B3);
}

// ---------------------------------------------------------------- chunk-level scan, 8-wide pipelined
__global__ __launch_bounds__(256) void scanB(const float* __restrict__ cAB, float* __restrict__ cHin) {
  const int b = blockIdx.x, ch = threadIdx.x;
  const float* base = cAB + (size_t)b * NC * 2 * H_ + ch;
  float* out = cHin + (size_t)b * NC * H_ + ch;
  float a[8], bb[8], an[8], bn[8];
  #pragma unroll
  for (int i = 0; i < 8; ++i) { a[i] = base[(size_t)i * 2 * H_]; bb[i] = base[(size_t)i * 2 * H_ + H_]; }
  float hp = 0.5f;  // h_0 = g(0)
  for (int tile = 0; tile < NC / 8; ++tile) {
    if (tile < NC / 8 - 1) {
      const float* nb = base + (size_t)(tile + 1) * 8 * 2 * H_;
      #pragma unroll
      for (int i = 0; i < 8; ++i) { an[i] = nb[(size_t)i * 2 * H_]; bn[i] = nb[(size_t)i * 2 * H_ + H_]; }
    }
    #pragma unroll
    for (int i = 0; i < 8; ++i) {
      out[(size_t)(tile * 8 + i) * H_] = hp;
      hp = a[i] * hp + bb[i];
    }
    #pragma unroll
    for (int i = 0; i < 8; ++i) { a[i] = an[i]; bb[i] = bn[i]; }
  }
}

// ---------------------------------------------------------------- shared GEMM body, 8-wave: wave owns 2 col-groups
__device__ __forceinline__ void gemm_tile8(const char* smem, const bf16* __restrict__ Wp,
                                           int lane, int wave,
                                           f32x4 (&accG)[2][2], f32x4 (&accH)[2][2]) {
  const int l15 = lane & 15, lhi = lane >> 4;
  #pragma unroll
  for (int kk = 0; kk < 8; ++kk) {
    const int kb = kk * 64 + lhi * 16;
    bf16x8 af[2], bG[2], bH[2];
    #pragma unroll
    for (int ni = 0; ni < 2; ++ni) {
      bG[ni] = *(const bf16x8*)(Wp + ((size_t)(kk * 2048 + (wave * 2 + ni) * 64 + lane)) * 8);
      bH[ni] = *(const bf16x8*)(Wp + ((size_t)(kk * 2048 + (16 + wave * 2 + ni) * 64 + lane)) * 8);
    }
    #pragma unroll
    for (int mi = 0; mi < 2; ++mi) {
      const int r = mi * 16 + l15;
      af[mi] = *(const bf16x8*)(smem + ATS(r, kb));
    }
    #pragma unroll
    for (int mi = 0; mi < 2; ++mi)
      #pragma unroll
      for (int ni = 0; ni < 2; ++ni) {
        accG[mi][ni] = __builtin_amdgcn_mfma_f32_16x16x32_bf16(af[mi], bG[ni], accG[mi][ni], 0, 0, 0);
        accH[mi][ni] = __builtin_amdgcn_mfma_f32_16x16x32_bf16(af[mi], bH[ni], accH[mi][ni], 0, 0, 0);
      }
  }
}

// epilogue (8-wave, 2 ni per wave): transform + residual fold; wave-private LDS transpose
// -> coalesced [ch][t] uint4 stores; shuffle-compose -> cAB
__device__ __forceinline__ void epilogue_fold8(
    const f32x4 (&accG)[2][2], const f32x4 (&accH)[2][2],
    const float* __restrict__ bias, int lane, int wave,
    const char* __restrict__ smemA,           // residual tile (bf16, ATS layout)
    const float* __restrict__ hm1s,           // per-channel residual value at row -1 (LDS)
    unsigned int* __restrict__ scr,           // per-wave 512-u32 LDS scratch
    uint4* __restrict__ ghc4, bool doStore,
    float* __restrict__ o) {
  const int l15 = lane & 15, lhi = lane >> 4;
  #pragma unroll
  for (int ni = 0; ni < 2; ++ni) {
    const int colG = wave * 32 + ni * 16 + l15;
    const float bg = bias[colG], bh = bias[colG + 256];
    float segA[2], segB[2];
    #pragma unroll
    for (int mi = 0; mi < 2; ++mi) {
      const int r0 = mi * 16 + lhi * 4;
      float hprev = (r0 == 0) ? hm1s[colG]
                  : b2f(*(const unsigned short*)(smemA + ATS(r0 - 1, colG * 2)));
      float Aa = 1.0f, Bb = 0.0f;
      unsigned int pk[4];
      #pragma unroll
      for (int j = 0; j < 4; ++j) {
        float a, btv;
        step_ab(accG[mi][ni][j] + bg, accH[mi][ni][j] + bh, a, btv);
        float hcurr = b2f(*(const unsigned short*)(smemA + ATS(r0 + j, colG * 2)));
        float bp = btv + hcurr - a * hprev;   // fold residual into b'
        hprev = hcurr;
        const unsigned short ua = f2b(a), ub = f2b(bp);
        pk[j] = ((unsigned int)ua << 16) | ub;
        const float ar = b2f(ua), br = b2f(ub);  // rounded, matches replay
        Aa = ar * Aa; Bb = ar * Bb + br;
      }
      if (doStore) {
        unsigned int* wp = scr + l15 * 32 + (((mi * 16 + lhi * 4)) ^ ((l15 & 7) << 2));
        *(uint4*)wp = make_uint4(pk[0], pk[1], pk[2], pk[3]);
      }
      segA[mi] = Aa; segB[mi] = Bb;
    }
    if (doStore) {
      #pragma unroll
      for (int s = 0; s < 2; ++s) {
        const int lin = s * 64 + lane;
        const int ch = lin >> 3, uq = lin & 7;
        uint4 v = *(const uint4*)(scr + ch * 32 + ((uq * 4) ^ ((ch & 7) << 2)));
        ghc4[(size_t)(wave * 32 + ni * 16) * 8 + lin] = v;   // lane-linear, coalesced
      }
    }
    #pragma unroll
    for (int mi = 0; mi < 2; ++mi) {
      float A = segA[mi], Bv = segB[mi];
      {
        float Ap = __shfl_xor(A, 16), Bp = __shfl_xor(Bv, 16);
        float Bn = (lhi & 1) ? (A * Bp + Bv) : (Ap * Bv + Bp);
        A = A * Ap; Bv = Bn;
      }
      {
        float Ap = __shfl_xor(A, 32), Bp = __shfl_xor(Bv, 32);
        float Bn = (lhi & 2) ? (A * Bp + Bv) : (Ap * Bv + Bp);
        A = A * Ap; Bv = Bn;
      }
      segA[mi] = A; segB[mi] = Bv;
    }
    const float Ac = segA[1] * segA[0];
    const float Bc = segA[1] * segB[0] + segB[1];
    if (lhi == 0) { o[colG] = Ac; o[H_ + colG] = Bc; }
  }
}

// ---------------------------------------------------------------- K1: fused layer-0 replay + layer-1 GEMM + fold
__global__ __launch_bounds__(512, 4) void l0_gemm_scanA(
    const int* __restrict__ x, const float* __restrict__ T0,
    const float* __restrict__ cHin0,
    const bf16* __restrict__ Wp, const float* __restrict__ bias,
    unsigned int* __restrict__ gh2, float* __restrict__ cAB) {
  __shared__ __align__(16) char smem[16384];       // A tile (h0, bf16, ATS)
  __shared__ unsigned int scrs[8][512];            // per-wave transpose scratch
  __shared__ float hm1s[256];                      // h0 at row -1 per channel
  __shared__ int xs[32];
  const int bid = blockIdx.x;
  const int c = bid & (NC - 1), b = bid >> 7;
  const size_t row0 = (size_t)b * S_ + (size_t)c * L_;
  const int tid = threadIdx.x, lane = tid & 63, wave = tid >> 6;

  if (tid < 32) xs[tid] = x[row0 + tid];
  float state = 0.0f;
  if (tid < 256) {
    state = cHin0[((size_t)b * NC + c) * H_ + tid];
    float hm1 = 0.0f;
    if (c > 0) hm1 = b2f(f2b(state + T0[(size_t)x[row0 - 1] * 768 + 512 + tid]));
    hm1s[tid] = hm1;
  }
  __syncthreads();
  if (tid < 256) {
    #pragma unroll 8
    for (int t = 0; t < L_; ++t) {
      const float* tp = T0 + (size_t)xs[t] * 768;
      float a = tp[tid], bt = tp[256 + tid], r = tp[512 + tid];
      state = a * state + bt;
      *(unsigned short*)(smem + ATS(t, tid * 2)) = f2b(state + r);
    }
  }
  __syncthreads();

  f32x4 accG[2][2] = {}, accH[2][2] = {};
  gemm_tile8(smem, Wp, lane, wave, accG, accH);
  uint4* ghc4 = (uint4*)(gh2 + ((size_t)b * NC + c) * (L_ * 256));
  epilogue_fold8(accG, accH, bias, lane, wave, smem, hm1s, scrs[wave], ghc4, true,
                 cAB + ((size_t)b * NC + c) * 2 * H_);
}

// ---------------------------------------------------------------- K2: fused y1-replay + layer-2 GEMM + fold
__global__ __launch_bounds__(512, 4) void scan_gemm(
    unsigned int* __restrict__ gh2, const float* __restrict__ cHin,
    const bf16* __restrict__ Wp, const float* __restrict__ bias,
    float* __restrict__ cAB) {
  __shared__ __align__(16) char smem[16384];
  __shared__ unsigned int scrs[8][512];
  __shared__ float hm1s[256];
  const int bid = blockIdx.x;
  const int c = bid & (NC - 1), b = bid >> 7;
  const int tid = threadIdx.x, lane = tid & 63, wave = tid >> 6;

  if (tid < 256) {
    float hp = cHin[((size_t)b * NC + c) * H_ + tid];
    hm1s[tid] = hp;                   // y1 boundary state = residual row -1 for layer 2
    const uint4* pq = (const uint4*)(gh2 + ((size_t)b * NC + c) * (L_ * 256)) + tid * 8;
    #pragma unroll
    for (int tt = 0; tt < 8; ++tt) {
      uint4 v = pq[tt];
      hp = b2f(v.x >> 16) * hp + b2f(v.x & 0xffffu);
      *(unsigned short*)(smem + ATS(tt * 4 + 0, tid * 2)) = f2b(hp);
      hp = b2f(v.y >> 16) * hp + b2f(v.y & 0xffffu);
      *(unsigned short*)(smem + ATS(tt * 4 + 1, tid * 2)) = f2b(hp);
      hp = b2f(v.z >> 16) * hp + b2f(v.z & 0xffffu);
      *(unsigned short*)(smem + ATS(tt * 4 + 2, tid * 2)) = f2b(hp);
      hp = b2f(v.w >> 16) * hp + b2f(v.w & 0xffffu);
      *(unsigned short*)(smem + ATS(tt * 4 + 3, tid * 2)) = f2b(hp);
    }
  }
  __syncthreads();

  f32x4 accG[2][2] = {}, accH[2][2] = {};
  gemm_tile8(smem, Wp, lane, wave, accG, accH);
  uint4* ghc4 = (uint4*)(gh2 + ((size_t)b * NC + c) * (L_ * 256));   // in-place overwrite (own chunk only)
  epilogue_fold8(accG, accH, bias, lane, wave, smem, hm1s, scrs[wave], ghc4, c >= NC - 1,
                 cAB + ((size_t)b * NC + c) * 2 * H_);
}

// ---------------------------------------------------------------- K3: tail replay (last chunk, layer 2; write-only)
__global__ __launch_bounds__(256) void scanC_tail(const unsigned int* __restrict__ gh2,
                                                  const float* __restrict__ cHin,
                                                  bf16* __restrict__ h) {
  const int b = blockIdx.x;
  const int c = NC - 1;
  const int ch = threadIdx.x;
  const size_t row0 = (size_t)b * S_ + (size_t)c * L_;
  float hp = cHin[((size_t)b * NC + c) * H_ + ch];
  const uint4* pq = (const uint4*)(gh2 + ((size_t)b * NC + c) * (L_ * 256)) + ch * 8;
  unsigned short* hio = (unsigned short*)h + row0 * 256 + ch;
  #pragma unroll
  for (int tt = 0; tt < 8; ++tt) {
    uint4 v = pq[tt];
    hp = b2f(v.x >> 16) * hp + b2f(v.x & 0xffffu); hio[(tt * 4 + 0) * 256] = f2b(hp);
    hp = b2f(v.y >> 16) * hp + b2f(v.y & 0xffffu); hio[(tt * 4 + 1) * 256] = f2b(hp);
    hp = b2f(v.z >> 16) * hp + b2f(v.z & 0xffffu); hio[(tt * 4 + 2) * 256] = f2b(hp);
    hp = b2f(v.w >> 16) * hp + b2f(v.w & 0xffffu); hio[(tt * 4 + 3) * 256] = f2b(hp);
  }
}

// ---------------------------------------------------------------- output logits (last NM positions)
__global__ __launch_bounds__(256) void out_logits(const bf16* __restrict__ h,
                                                  const float* __restrict__ Wout,
                                                  const float* __restrict__ bout,
                                                  float* __restrict__ out) {
  const int r = blockIdx.x;
  const int b = r >> 4, si = r & 15;
  const int v = threadIdx.x;
  __shared__ float hs[H_];
  const size_t t = (size_t)b * S_ + (S_ - NM_ + si);
  hs[v] = b2f(((const unsigned short*)h)[t * H_ + v]);
  __syncthreads();
  float acc = bout[v];
  const float4* w4 = (const float4*)(Wout + (size_t)v * H_);
  #pragma unroll 8
  for (int k = 0; k < H_ / 4; ++k) {
    float4 wv = w4[k];
    float4 hv = *(const float4*)(hs + 4 * k);
    acc += wv.x * hv.x + wv.y * hv.y + wv.z * hv.z + wv.w * hv.w;
  }
  out[(size_t)r * V_ + v] = acc;
}

// ----------------------------------------------------------------
extern "C" void kernel_launch(void* const* d_in, const int* in_sizes, int n_in,
                              void* d_out, int out_size, void* d_ws, size_t ws_size,
                              hipStream_t stream) {
  const int*   x      = (const int*)d_in[0];
  const float* emb    = (const float*)d_in[1];
  const float* W0     = (const float*)d_in[2];
  const float* b0     = (const float*)d_in[3];
  const float* Wl     = (const float*)d_in[4];
  const float* bl     = (const float*)d_in[5];
  const float* Walign = (const float*)d_in[6];
  const float* Wout   = (const float*)d_in[7];
  const float* bout   = (const float*)d_in[8];
  (void)in_sizes; (void)n_in; (void)out_size; (void)ws_size;

  char* ws = (char*)d_ws;
  size_t off = 0;
  unsigned int* gh2 = (unsigned int*)(ws + off); off += (size_t)B_ * S_ * 256 * 4;  // 134 MB packed (a|b'), [ch][t]
  bf16*  h    = (bf16*)(ws + off);  off += (size_t)B_ * S_ * H_ * 2;     // 67 MB (only tail rows used: y2)
  float* cAB  = (float*)(ws + off); off += (size_t)B_ * NC * 2 * H_ * 4; // 8.4 MB (reused per layer)
  float* cHin = (float*)(ws + off); off += (size_t)B_ * NC * H_ * 4;     // 4.2 MB (reused)
  float* T0   = (float*)(ws + off); off += (size_t)V_ * 768 * 4;         // 768 KB
  bf16*  Wpk  = (bf16*)(ws + off);  off += (size_t)2 * GH * H_ * 2;      // 512 KB

  build_tables<<<256, 256, 0, stream>>>(emb, W0, b0, Walign, Wl, T0, Wpk);

  dim3 gscan(NC / 4, B_);
  // layer 0: chunk summaries + boundary states only (h0 never materialized)
  scanA_l0<<<gscan, 256, 0, stream>>>(x, T0, cAB);
  scanB<<<B_, 256, 0, stream>>>(cAB, cHin);

  const bf16* Wpk2 = Wpk + (size_t)GH * H_;
  // layer 1: fused l0-replay + GEMM + fold -> gh2 (a1|b1'), chunk totals
  l0_gemm_scanA<<<B_ * NC, 512, 0, stream>>>(x, T0, cHin, Wpk, bl, gh2, cAB);
  scanB<<<B_, 256, 0, stream>>>(cAB, cHin);
  // layer 2: fused y1-replay + GEMM2 + fold; last chunk overwrites gh2 with (a2|b2')
  scan_gemm<<<B_ * NC, 512, 0, stream>>>(gh2, cHin, Wpk2, bl + GH, cAB);
  scanB<<<B_, 256, 0, stream>>>(cAB, cHin);
  scanC_tail<<<B_, 256, 0, stream>>>(gh2, cHin, h);

  out_logits<<<B_ * NM_, 256, 0, stream>>>(h, Wout, bout, (float*)d_out);
}

// Round 15
// 203.784 us; speedup vs baseline: 1.0505x; 1.0505x over previous
//
#include <hip/hip_runtime.h>
#include <hip/hip_bf16.h>

using bf16 = __hip_bfloat16;

constexpr int B_ = 32, S_ = 4096, V_ = 256, E_ = 128, H_ = 256, NM_ = 16;
constexpr int GH = 2 * H_;        // 512
constexpr int NC = 128, L_ = 32;  // chunked scan: 128 chunks of 32 steps

typedef __attribute__((ext_vector_type(8))) short bf16x8;
typedef __attribute__((ext_vector_type(4))) float f32x4;

__device__ __forceinline__ float b2f(unsigned short u) {
  union { float f; unsigned int i; } x; x.i = ((unsigned int)u) << 16; return x.f;
}
// RNE bf16 pack, no NaN path (values finite here)
__device__ __forceinline__ unsigned short f2b(float f) {
  unsigned int i = __builtin_bit_cast(unsigned int, f);
  return (unsigned short)((i + 0x7fffu + ((i >> 16) & 1u)) >> 16);
}
// 1-op unpack of packed (a|b) u32: hi -> float, lo -> float
__device__ __forceinline__ float hi_f(unsigned int u) {
  union { float f; unsigned int i; } x; x.i = u & 0xffff0000u; return x.f;
}
__device__ __forceinline__ float lo_f(unsigned int u) {
  union { float f; unsigned int i; } x; x.i = u << 16; return x.f;
}
// packed RNE bf16 pair: hi=bf16(ha), lo=bf16(lb) -- single v_cvt_pk_bf16_f32
__device__ __forceinline__ unsigned int cvt_pk(float lb, float ha) {
  unsigned int r;
  asm("v_cvt_pk_bf16_f32 %0, %1, %2" : "=v"(r) : "v"(lb), "v"(ha));
  return r;
}

// h_t = a*h_{t-1} + bt;  a = sigmoid(-gate), bt = sigmoid(gate)*g(hid)
__device__ __forceinline__ void step_ab(float gate, float hid, float& a, float& bt) {
  const float LOG2E = 1.4426950408889634f;
  float e  = __builtin_amdgcn_exp2f(gate * LOG2E);
  a = __builtin_amdgcn_rcpf(1.0f + e);
  float sn = __builtin_amdgcn_rcpf(1.0f + __builtin_amdgcn_exp2f(-hid * LOG2E));
  float g  = (hid >= 0.0f) ? (hid + 0.5f) : sn;
  bt = (1.0f - a) * g;
}

// A-tile LDS swizzle: logical (row, byte-col) -> LDS byte offset
#define ATS(row, bcol) (((row) << 9) | ((bcol) ^ (((row) & 7) << 4)))

// gh2 layout: [b][c][ch][t] u32 (a | b' packed bf16); chunk base (u32): (b*NC+c)*256*32
// b' carries the folded residual: replaying y_t = a y_{t-1} + b' yields h_scan + residual.

// ---------------------------------------------------------------- tables
__global__ __launch_bounds__(256) void build_tables(
    const float* __restrict__ emb, const float* __restrict__ W0,
    const float* __restrict__ b0, const float* __restrict__ Walign,
    const float* __restrict__ Wl, float* __restrict__ T0, bf16* __restrict__ Wpk) {
  const int v = blockIdx.x;
  const int t = threadIdx.x;
  __shared__ float e[E_];
  if (t < E_) e[t] = emb[v * E_ + t];
  __syncthreads();
  const float4* w0g = (const float4*)(W0 + (size_t)t * E_);
  const float4* w0h = (const float4*)(W0 + (size_t)(t + 256) * E_);
  const float4* wal = (const float4*)(Walign + (size_t)t * E_);
  float g = b0[t], hd = b0[t + 256], al = 0.0f;
  #pragma unroll 8
  for (int k = 0; k < E_ / 4; ++k) {
    float4 ev = *(const float4*)(e + 4 * k);
    float4 ga = w0g[k]; g  += ga.x * ev.x + ga.y * ev.y + ga.z * ev.z + ga.w * ev.w;
    float4 hb = w0h[k]; hd += hb.x * ev.x + hb.y * ev.y + hb.z * ev.z + hb.w * ev.w;
    float4 aw = wal[k]; al += aw.x * ev.x + aw.y * ev.y + aw.z * ev.z + aw.w * ev.w;
  }
  float a, btv; step_ab(g, hd, a, btv);
  T0[(size_t)v * 768 + t]       = a;
  T0[(size_t)v * 768 + 256 + t] = btv;
  T0[(size_t)v * 768 + 512 + t] = al;

  const int fid = v * 256 + t;
  if (fid < 32768) {
    const int layer = fid >> 14;
    const int kk   = (fid >> 11) & 7;
    const int grp  = (fid >> 6) & 31;
    const int lane = fid & 63;
    const int row = grp * 16 + (lane & 15);
    const int k0  = kk * 32 + (lane >> 4) * 8;
    const float* src = Wl + (((size_t)layer * 512 + row) * 256 + k0);
    bf16* dst = Wpk + (size_t)fid * 8;
    #pragma unroll
    for (int e2 = 0; e2 < 8; ++e2) dst[e2] = __float2bfloat16(src[e2]);
  }
}

// ---------------------------------------------------------------- layer-0 scan A
__global__ __launch_bounds__(256) void scanA_l0(const int* __restrict__ x, const float* __restrict__ T0,
                                                float* __restrict__ cAB) {
  const int b = blockIdx.y;
  const int wv = threadIdx.x >> 6, lane = threadIdx.x & 63;
  const int c = blockIdx.x * 4 + wv;
  const int t4 = lane * 4;
  const int* xp = x + (size_t)b * S_ + (size_t)c * L_;
  float A0=1,A1=1,A2=1,A3=1, B0=0,B1=0,B2=0,B3=0;
  #pragma unroll 4
  for (int t = 0; t < L_; ++t) {
    const float* tp = T0 + (size_t)xp[t] * 768;
    float4 a4 = *(const float4*)(tp + t4);
    float4 b4 = *(const float4*)(tp + 256 + t4);
    A0 = a4.x*A0; B0 = a4.x*B0 + b4.x;
    A1 = a4.y*A1; B1 = a4.y*B1 + b4.y;
    A2 = a4.z*A2; B2 = a4.z*B2 + b4.z;
    A3 = a4.w*A3; B3 = a4.w*B3 + b4.w;
  }
  float* o = cAB + (size_t)(b * NC + c) * 2 * H_;
  *(float4*)(o + t4)      = make_float4(A0, A1, A2, A3);
  *(float4*)(o + H_ + t4) = make_float4(B0, B1, B2, B3);
}

// ---------------------------------------------------------------- chunk-level scan, 8-wide pipelined
__global__ __launch_bounds__(256) void scanB(const float* __restrict__ cAB, float* __restrict__ cHin) {
  const int b = blockIdx.x, ch = threadIdx.x;
  const float* base = cAB + (size_t)b * NC * 2 * H_ + ch;
  float* out = cHin + (size_t)b * NC * H_ + ch;
  float a[8], bb[8], an[8], bn[8];
  #pragma unroll
  for (int i = 0; i < 8; ++i) { a[i] = base[(size_t)i * 2 * H_]; bb[i] = base[(size_t)i * 2 * H_ + H_]; }
  float hp = 0.5f;  // h_0 = g(0)
  for (int tile = 0; tile < NC / 8; ++tile) {
    if (tile < NC / 8 - 1) {
      const float* nb = base + (size_t)(tile + 1) * 8 * 2 * H_;
      #pragma unroll
      for (int i = 0; i < 8; ++i) { an[i] = nb[(size_t)i * 2 * H_]; bn[i] = nb[(size_t)i * 2 * H_ + H_]; }
    }
    #pragma unroll
    for (int i = 0; i < 8; ++i) {
      out[(size_t)(tile * 8 + i) * H_] = hp;
      hp = a[i] * hp + bb[i];
    }
    #pragma unroll
    for (int i = 0; i < 8; ++i) { a[i] = an[i]; bb[i] = bn[i]; }
  }
}

// ---------------------------------------------------------------- shared GEMM body (32 x 512 = A[32,256] @ Wpk)
__device__ __forceinline__ void gemm_tile(const char* smem, const bf16* __restrict__ Wp,
                                          int lane, int wave,
                                          f32x4 (&accG)[2][4], f32x4 (&accH)[2][4]) {
  const int l15 = lane & 15, lhi = lane >> 4;
  #pragma unroll
  for (int kk = 0; kk < 8; ++kk) {
    const int kb = kk * 64 + lhi * 16;
    bf16x8 af[2], bG[4], bH[4];
    #pragma unroll
    for (int ni = 0; ni < 4; ++ni) {
      bG[ni] = *(const bf16x8*)(Wp + ((size_t)(kk * 2048 + (wave * 4 + ni) * 64 + lane)) * 8);
      bH[ni] = *(const bf16x8*)(Wp + ((size_t)(kk * 2048 + (16 + wave * 4 + ni) * 64 + lane)) * 8);
    }
    #pragma unroll
    for (int mi = 0; mi < 2; ++mi) {
      const int r = mi * 16 + l15;
      af[mi] = *(const bf16x8*)(smem + ATS(r, kb));
    }
    #pragma unroll
    for (int mi = 0; mi < 2; ++mi)
      #pragma unroll
      for (int ni = 0; ni < 4; ++ni) {
        accG[mi][ni] = __builtin_amdgcn_mfma_f32_16x16x32_bf16(af[mi], bG[ni], accG[mi][ni], 0, 0, 0);
        accH[mi][ni] = __builtin_amdgcn_mfma_f32_16x16x32_bf16(af[mi], bH[ni], accH[mi][ni], 0, 0, 0);
      }
  }
}

// epilogue: transform + residual fold (b' = b + r_t - a*r_{t-1}); packed via v_cvt_pk_bf16_f32;
// wave-private LDS transpose -> coalesced [ch][t] uint4 stores; shuffle-compose -> cAB
__device__ __forceinline__ void epilogue_fold(
    const f32x4 (&accG)[2][4], const f32x4 (&accH)[2][4],
    const float* __restrict__ bias, int lane, int wave,
    const char* __restrict__ smemA,           // residual tile (bf16, ATS layout)
    const float* __restrict__ hm1s,           // per-channel residual value at row -1 (LDS)
    unsigned int* __restrict__ scr,           // per-wave 512-u32 LDS scratch
    uint4* __restrict__ ghc4, bool doStore,
    float* __restrict__ o) {
  const int l15 = lane & 15, lhi = lane >> 4;
  #pragma unroll
  for (int ni = 0; ni < 4; ++ni) {
    const int colG = wave * 64 + ni * 16 + l15;
    const float bg = bias[colG], bh = bias[colG + 256];
    float segA[2], segB[2];
    #pragma unroll
    for (int mi = 0; mi < 2; ++mi) {
      const int r0 = mi * 16 + lhi * 4;
      float hprev = (r0 == 0) ? hm1s[colG]
                  : b2f(*(const unsigned short*)(smemA + ATS(r0 - 1, colG * 2)));
      float Aa = 1.0f, Bb = 0.0f;
      unsigned int pk[4];
      #pragma unroll
      for (int j = 0; j < 4; ++j) {
        float a, btv;
        step_ab(accG[mi][ni][j] + bg, accH[mi][ni][j] + bh, a, btv);
        float hcurr = b2f(*(const unsigned short*)(smemA + ATS(r0 + j, colG * 2)));
        float bp = btv + hcurr - a * hprev;   // fold residual into b'
        hprev = hcurr;
        pk[j] = cvt_pk(bp, a);                // lo=bf16(bp), hi=bf16(a) -- 1 VALU op
        const float ar = hi_f(pk[j]), br = lo_f(pk[j]);  // rounded, matches replay
        Aa = ar * Aa; Bb = ar * Bb + br;
      }
      if (doStore) {
        unsigned int* wp = scr + l15 * 32 + (((mi * 16 + lhi * 4)) ^ ((l15 & 7) << 2));
        *(uint4*)wp = make_uint4(pk[0], pk[1], pk[2], pk[3]);
      }
      segA[mi] = Aa; segB[mi] = Bb;
    }
    if (doStore) {
      #pragma unroll
      for (int s = 0; s < 2; ++s) {
        const int lin = s * 64 + lane;
        const int ch = lin >> 3, uq = lin & 7;
        uint4 v = *(const uint4*)(scr + ch * 32 + ((uq * 4) ^ ((ch & 7) << 2)));
        ghc4[(size_t)(wave * 64 + ni * 16) * 8 + lin] = v;   // lane-linear, coalesced
      }
    }
    #pragma unroll
    for (int mi = 0; mi < 2; ++mi) {
      float A = segA[mi], Bv = segB[mi];
      {
        float Ap = __shfl_xor(A, 16), Bp = __shfl_xor(Bv, 16);
        float Bn = (lhi & 1) ? (A * Bp + Bv) : (Ap * Bv + Bp);
        A = A * Ap; Bv = Bn;
      }
      {
        float Ap = __shfl_xor(A, 32), Bp = __shfl_xor(Bv, 32);
        float Bn = (lhi & 2) ? (A * Bp + Bv) : (Ap * Bv + Bp);
        A = A * Ap; Bv = Bn;
      }
      segA[mi] = A; segB[mi] = Bv;
    }
    const float Ac = segA[1] * segA[0];
    const float Bc = segA[1] * segB[0] + segB[1];
    if (lhi == 0) { o[colG] = Ac; o[H_ + colG] = Bc; }
  }
}

// ---------------------------------------------------------------- K1: fused layer-0 replay + layer-1 GEMM + fold
// h0 never touches HBM: per-channel replay from T0 gathers + cHin0 -> LDS A-tile.
__global__ __launch_bounds__(256, 4) void l0_gemm_scanA(
    const int* __restrict__ x, const float* __restrict__ T0,
    const float* __restrict__ cHin0,
    const bf16* __restrict__ Wp, const float* __restrict__ bias,
    unsigned int* __restrict__ gh2, float* __restrict__ cAB) {
  __shared__ __align__(16) char smem[16384];       // A tile (h0, bf16, ATS)
  __shared__ unsigned int scrs[4][512];            // per-wave transpose scratch
  __shared__ float hm1s[256];                      // h0 at row -1 per channel
  __shared__ int xs[32];
  const int bid = blockIdx.x;
  const int c = bid & (NC - 1), b = bid >> 7;
  const size_t row0 = (size_t)b * S_ + (size_t)c * L_;
  const int tid = threadIdx.x, lane = tid & 63, wave = tid >> 6;
  const int ch = tid;

  if (tid < 32) xs[tid] = x[row0 + tid];
  float state = cHin0[((size_t)b * NC + c) * H_ + ch];
  {
    float hm1 = 0.0f;
    if (c > 0) {
      const int xm1 = x[row0 - 1];
      hm1 = b2f(f2b(state + T0[(size_t)xm1 * 768 + 512 + ch]));
    }
    hm1s[ch] = hm1;
  }
  __syncthreads();
  #pragma unroll 8
  for (int t = 0; t < L_; ++t) {
    const float* tp = T0 + (size_t)xs[t] * 768;
    float a = tp[ch], bt = tp[256 + ch], r = tp[512 + ch];
    state = a * state + bt;
    *(unsigned short*)(smem + ATS(t, ch * 2)) = f2b(state + r);
  }
  __syncthreads();

  f32x4 accG[2][4] = {}, accH[2][4] = {};
  gemm_tile(smem, Wp, lane, wave, accG, accH);
  uint4* ghc4 = (uint4*)(gh2 + ((size_t)b * NC + c) * (L_ * 256));
  epilogue_fold(accG, accH, bias, lane, wave, smem, hm1s, scrs[wave], ghc4, true,
                cAB + ((size_t)b * NC + c) * 2 * H_);
}

// ---------------------------------------------------------------- K2: fused y1-replay + layer-2 GEMM + fold
__global__ __launch_bounds__(256, 4) void scan_gemm(
    unsigned int* __restrict__ gh2, const float* __restrict__ cHin,
    const bf16* __restrict__ Wp, const float* __restrict__ bias,
    float* __restrict__ cAB) {
  __shared__ __align__(16) char smem[16384];
  __shared__ unsigned int scrs[4][512];
  __shared__ float hm1s[256];
  const int bid = blockIdx.x;
  const int c = bid & (NC - 1), b = bid >> 7;
  const int tid = threadIdx.x, lane = tid & 63, wave = tid >> 6;
  const int ch = tid;

  // replay y1 for this chunk straight into the LDS A-tile (b' already carries residual)
  float hp = cHin[((size_t)b * NC + c) * H_ + ch];
  hm1s[ch] = hp;                      // y1 boundary state = residual row -1 for layer 2
  const uint4* pq = (const uint4*)(gh2 + ((size_t)b * NC + c) * (L_ * 256)) + ch * 8;
  #pragma unroll
  for (int tt = 0; tt < 8; ++tt) {
    uint4 v = pq[tt];
    hp = hi_f(v.x) * hp + lo_f(v.x);
    *(unsigned short*)(smem + ATS(tt * 4 + 0, ch * 2)) = f2b(hp);
    hp = hi_f(v.y) * hp + lo_f(v.y);
    *(unsigned short*)(smem + ATS(tt * 4 + 1, ch * 2)) = f2b(hp);
    hp = hi_f(v.z) * hp + lo_f(v.z);
    *(unsigned short*)(smem + ATS(tt * 4 + 2, ch * 2)) = f2b(hp);
    hp = hi_f(v.w) * hp + lo_f(v.w);
    *(unsigned short*)(smem + ATS(tt * 4 + 3, ch * 2)) = f2b(hp);
  }
  __syncthreads();

  f32x4 accG[2][4] = {}, accH[2][4] = {};
  gemm_tile(smem, Wp, lane, wave, accG, accH);
  uint4* ghc4 = (uint4*)(gh2 + ((size_t)b * NC + c) * (L_ * 256));   // in-place overwrite (own chunk only)
  epilogue_fold(accG, accH, bias, lane, wave, smem, hm1s, scrs[wave], ghc4, c >= NC - 1,
                cAB + ((size_t)b * NC + c) * 2 * H_);
}

// ---------------------------------------------------------------- K3: tail replay (last chunk, layer 2; write-only)
__global__ __launch_bounds__(256) void scanC_tail(const unsigned int* __restrict__ gh2,
                                                  const float* __restrict__ cHin,
                                                  bf16* __restrict__ h) {
  const int b = blockIdx.x;
  const int c = NC - 1;
  const int ch = threadIdx.x;
  const size_t row0 = (size_t)b * S_ + (size_t)c * L_;
  float hp = cHin[((size_t)b * NC + c) * H_ + ch];
  const uint4* pq = (const uint4*)(gh2 + ((size_t)b * NC + c) * (L_ * 256)) + ch * 8;
  unsigned short* hio = (unsigned short*)h + row0 * 256 + ch;
  #pragma unroll
  for (int tt = 0; tt < 8; ++tt) {
    uint4 v = pq[tt];
    hp = hi_f(v.x) * hp + lo_f(v.x); hio[(tt * 4 + 0) * 256] = f2b(hp);
    hp = hi_f(v.y) * hp + lo_f(v.y); hio[(tt * 4 + 1) * 256] = f2b(hp);
    hp = hi_f(v.z) * hp + lo_f(v.z); hio[(tt * 4 + 2) * 256] = f2b(hp);
    hp = hi_f(v.w) * hp + lo_f(v.w); hio[(tt * 4 + 3) * 256] = f2b(hp);
  }
}

// ---------------------------------------------------------------- output logits (last NM positions)
__global__ __launch_bounds__(256) void out_logits(const bf16* __restrict__ h,
                                                  const float* __restrict__ Wout,
                                                  const float* __restrict__ bout,
                                                  float* __restrict__ out) {
  const int r = blockIdx.x;
  const int b = r >> 4, si = r & 15;
  const int v = threadIdx.x;
  __shared__ float hs[H_];
  const size_t t = (size_t)b * S_ + (S_ - NM_ + si);
  hs[v] = b2f(((const unsigned short*)h)[t * H_ + v]);
  __syncthreads();
  float acc = bout[v];
  const float4* w4 = (const float4*)(Wout + (size_t)v * H_);
  #pragma unroll 8
  for (int k = 0; k < H_ / 4; ++k) {
    float4 wv = w4[k];
    float4 hv = *(const float4*)(hs + 4 * k);
    acc += wv.x * hv.x + wv.y * hv.y + wv.z * hv.z + wv.w * hv.w;
  }
  out[(size_t)r * V_ + v] = acc;
}

// ----------------------------------------------------------------
extern "C" void kernel_launch(void* const* d_in, const int* in_sizes, int n_in,
                              void* d_out, int out_size, void* d_ws, size_t ws_size,
                              hipStream_t stream) {
  const int*   x      = (const int*)d_in[0];
  const float* emb    = (const float*)d_in[1];
  const float* W0     = (const float*)d_in[2];
  const float* b0     = (const float*)d_in[3];
  const float* Wl     = (const float*)d_in[4];
  const float* bl     = (const float*)d_in[5];
  const float* Walign = (const float*)d_in[6];
  const float* Wout   = (const float*)d_in[7];
  const float* bout   = (const float*)d_in[8];
  (void)in_sizes; (void)n_in; (void)out_size; (void)ws_size;

  char* ws = (char*)d_ws;
  size_t off = 0;
  unsigned int* gh2 = (unsigned int*)(ws + off); off += (size_t)B_ * S_ * 256 * 4;  // 134 MB packed (a|b'), [ch][t]
  bf16*  h    = (bf16*)(ws + off);  off += (size_t)B_ * S_ * H_ * 2;     // 67 MB (only tail rows used: y2)
  float* cAB  = (float*)(ws + off); off += (size_t)B_ * NC * 2 * H_ * 4; // 8.4 MB (reused per layer)
  float* cHin = (float*)(ws + off); off += (size_t)B_ * NC * H_ * 4;     // 4.2 MB (reused)
  float* T0   = (float*)(ws + off); off += (size_t)V_ * 768 * 4;         // 768 KB
  bf16*  Wpk  = (bf16*)(ws + off);  off += (size_t)2 * GH * H_ * 2;      // 512 KB

  build_tables<<<256, 256, 0, stream>>>(emb, W0, b0, Walign, Wl, T0, Wpk);

  dim3 gscan(NC / 4, B_);
  // layer 0: chunk summaries + boundary states only (h0 never materialized)
  scanA_l0<<<gscan, 256, 0, stream>>>(x, T0, cAB);
  scanB<<<B_, 256, 0, stream>>>(cAB, cHin);

  const bf16* Wpk2 = Wpk + (size_t)GH * H_;
  // layer 1: fused l0-replay + GEMM + fold -> gh2 (a1|b1'), chunk totals
  l0_gemm_scanA<<<B_ * NC, 256, 0, stream>>>(x, T0, cHin, Wpk, bl, gh2, cAB);
  scanB<<<B_, 256, 0, stream>>>(cAB, cHin);
  // layer 2: fused y1-replay + GEMM2 + fold; last chunk overwrites gh2 with (a2|b2')
  scan_gemm<<<B_ * NC, 256, 0, stream>>>(gh2, cHin, Wpk2, bl + GH, cAB);
  scanB<<<B_, 256, 0, stream>>>(cAB, cHin);
  scanC_tail<<<B_, 256, 0, stream>>>(gh2, cHin, h);

  out_logits<<<B_ * NM_, 256, 0, stream>>>(h, Wout, bout, (float*)d_out);
}